// Round 3
// baseline (304.479 us; speedup 1.0000x reference)
//
#include <hip/hip_runtime.h>
#include <math.h>

#define N_NODES 50000
#define N_EDGES 800000
#define IN_DIM  128
#define OUT_DIM 64
#define LEAKY   0.01f

#define ROWS_PB  16
#define PROJ_NB  (N_NODES / ROWS_PB)     // 3125, exact

#define SCAN_B   1024
#define SCAN_NB  ((N_NODES + SCAN_B - 1) / SCAN_B)   // 49

// ---------------------------------------------------------------------------
// z = feat @ W ; az epilogue. ONE wave per block so feat addresses are
// provably wave-uniform -> scalar loads (s_load_dwordx4) feed v_fmac directly.
// Lane = output dim; 16 rows per block; W column load reused by all 16 rows.
__global__ __launch_bounds__(64) void proj_kernel(
        const float* __restrict__ feat, const float* __restrict__ W,
        const float* __restrict__ a,
        float* __restrict__ z, float* __restrict__ az_src, float* __restrict__ az_dst) {
    int lane = threadIdx.x;                    // 0..63 = output dim
    int row0 = blockIdx.x * ROWS_PB;           // uniform
    const float* __restrict__ frow = feat + (size_t)row0 * IN_DIM;

    float acc[ROWS_PB];
#pragma unroll
    for (int r = 0; r < ROWS_PB; ++r) acc[r] = 0.f;

#pragma unroll 4
    for (int k = 0; k < IN_DIM; ++k) {
        float wk = W[k * OUT_DIM + lane];      // coalesced, L1-hot, 16x reuse
#pragma unroll
        for (int r = 0; r < ROWS_PB; ++r)
            acc[r] = fmaf(frow[(size_t)r * IN_DIM + k], wk, acc[r]); // uniform -> SGPR
    }

    float a1 = a[lane], a2 = a[OUT_DIM + lane];
#pragma unroll
    for (int r = 0; r < ROWS_PB; ++r) {
        z[(size_t)(row0 + r) * OUT_DIM + lane] = acc[r];
        float s1 = acc[r] * a1;
        float s2 = acc[r] * a2;
#pragma unroll
        for (int off = 32; off > 0; off >>= 1) {
            s1 += __shfl_xor(s1, off, 64);
            s2 += __shfl_xor(s2, off, 64);
        }
        if (lane == r) { az_src[row0 + r] = s1; az_dst[row0 + r] = s2; }
    }
}

// ---------------------------------------------------------------------------
// degree histogram
__global__ __launch_bounds__(256) void hist_kernel(
        const int* __restrict__ dst, int* __restrict__ counts) {
    int i = blockIdx.x * 256 + threadIdx.x;
    if (i < N_EDGES) atomicAdd(&counts[dst[i]], 1);
}

// ---------------------------------------------------------------------------
// scan step 1: per-block exclusive scan, block totals out
__global__ __launch_bounds__(SCAN_B) void scan1_kernel(
        const int* __restrict__ counts, int* __restrict__ offsets,
        int* __restrict__ blocksums) {
    __shared__ int s[SCAN_B];
    int i = blockIdx.x * SCAN_B + threadIdx.x;
    int v = (i < N_NODES) ? counts[i] : 0;
    s[threadIdx.x] = v;
    __syncthreads();
    for (int off = 1; off < SCAN_B; off <<= 1) {
        int t = (threadIdx.x >= off) ? s[threadIdx.x - off] : 0;
        __syncthreads();
        s[threadIdx.x] += t;
        __syncthreads();
    }
    if (i < N_NODES) offsets[i] = s[threadIdx.x] - v;
    if (threadIdx.x == SCAN_B - 1) blocksums[blockIdx.x] = s[SCAN_B - 1];
}

// scan step 2: exclusive scan of block totals, one block
__global__ __launch_bounds__(64) void scan2_kernel(int* __restrict__ blocksums) {
    __shared__ int s[64];
    int tid = threadIdx.x;
    int v = (tid < SCAN_NB) ? blocksums[tid] : 0;
    s[tid] = v;
    __syncthreads();
    for (int off = 1; off < 64; off <<= 1) {
        int t = (tid >= off) ? s[tid - off] : 0;
        __syncthreads();
        s[tid] += t;
        __syncthreads();
    }
    if (tid < SCAN_NB) blocksums[tid] = s[tid] - v;
}

// scan step 3: add block offset; init cursor; seal offsets[N]
__global__ __launch_bounds__(SCAN_B) void scan3_kernel(
        int* __restrict__ offsets, int* __restrict__ cursor,
        const int* __restrict__ blocksums) {
    int i = blockIdx.x * SCAN_B + threadIdx.x;
    if (i < N_NODES) {
        int o = offsets[i] + blocksums[blockIdx.x];
        offsets[i] = o;
        cursor[i]  = o;
    }
    if (i == 0) offsets[N_NODES] = N_EDGES;
}

// ---------------------------------------------------------------------------
// CSR build: compute edge score once, write ONE 8B record (src, e) per edge
__global__ __launch_bounds__(256) void build_csr_kernel(
        const int* __restrict__ src, const int* __restrict__ dst,
        const float* __restrict__ az_src, const float* __restrict__ az_dst,
        int* __restrict__ cursor, float2* __restrict__ edge_rec) {
    int i = blockIdx.x * 256 + threadIdx.x;
    if (i >= N_EDGES) return;
    int s = src[i], t = dst[i];
    float v = az_src[s] + az_dst[t];
    float e = v > 0.f ? v : LEAKY * v;
    int pos = atomicAdd(&cursor[t], 1);
    float2 rec;
    rec.x = __int_as_float(s);
    rec.y = e;
    edge_rec[pos] = rec;                       // single 8B scatter
}

// ---------------------------------------------------------------------------
// fused per-node softmax + weighted aggregation. One wave per node, lane = dim.
__global__ __launch_bounds__(256) void node_fused_kernel(
        const int* __restrict__ offsets, const float2* __restrict__ edge_rec,
        const float* __restrict__ z, float* __restrict__ h) {
    int lane = threadIdx.x & 63;
    int w    = threadIdx.x >> 6;
    int t    = blockIdx.x * 4 + w;
    if (t >= N_NODES) return;
    int beg = offsets[t];
    int end = offsets[t + 1];

    float m = -INFINITY;
    for (int i = beg + lane; i < end; i += 64)
        m = fmaxf(m, edge_rec[i].y);
    for (int off = 32; off > 0; off >>= 1)
        m = fmaxf(m, __shfl_xor(m, off, 64));

    float ssum = 0.f;
    for (int i = beg + lane; i < end; i += 64)
        ssum += __expf(edge_rec[i].y - m);
    for (int off = 32; off > 0; off >>= 1)
        ssum += __shfl_xor(ssum, off, 64);
    float inv = (end > beg) ? 1.f / ssum : 0.f;

    float acc = 0.f;
    for (int i = beg; i < end; ++i) {
        float2 rc = edge_rec[i];               // wave-uniform 8B broadcast
        int   s  = __float_as_int(rc.x);
        float al = __expf(rc.y - m) * inv;
        acc = fmaf(al, z[(size_t)s * OUT_DIM + lane], acc);   // coalesced 256B row
    }
    h[(size_t)t * OUT_DIM + lane] = acc;
}

// ---------------------------------------------------------------------------
extern "C" void kernel_launch(void* const* d_in, const int* in_sizes, int n_in,
                              void* d_out, int out_size, void* d_ws, size_t ws_size,
                              hipStream_t stream) {
    const float* feat = (const float*)d_in[0];
    const int*   src  = (const int*)  d_in[1];
    const int*   dst  = (const int*)  d_in[2];
    const float* W    = (const float*)d_in[3];
    const float* a    = (const float*)d_in[4];
    float* h = (float*)d_out;

    // workspace layout (edge_rec first for 8B alignment)
    float2* edge_rec  = (float2*)d_ws;                       // E float2
    float*  z         = (float*)(edge_rec + N_EDGES);        // N*64
    float*  az_src    = z + (size_t)N_NODES * OUT_DIM;
    float*  az_dst    = az_src + N_NODES;
    int*    counts    = (int*)(az_dst + N_NODES);            // N
    int*    offsets   = counts + N_NODES;                    // N+1
    int*    cursor    = offsets + N_NODES + 1;               // N
    int*    blocksums = cursor + N_NODES;                    // 64

    hipMemsetAsync(counts, 0, sizeof(int) * N_NODES, stream);

    proj_kernel<<<PROJ_NB, 64, 0, stream>>>(feat, W, a, z, az_src, az_dst);

    int eblocks = (N_EDGES + 255) / 256;
    hist_kernel<<<eblocks, 256, 0, stream>>>(dst, counts);

    scan1_kernel<<<SCAN_NB, SCAN_B, 0, stream>>>(counts, offsets, blocksums);
    scan2_kernel<<<1, 64, 0, stream>>>(blocksums);
    scan3_kernel<<<SCAN_NB, SCAN_B, 0, stream>>>(offsets, cursor, blocksums);

    build_csr_kernel<<<eblocks, 256, 0, stream>>>(src, dst, az_src, az_dst,
                                                  cursor, edge_rec);

    node_fused_kernel<<<(N_NODES + 3) / 4, 256, 0, stream>>>(
        offsets, edge_rec, z, h);
}

// Round 4
// 268.233 us; speedup vs baseline: 1.1351x; 1.1351x over previous
//
#include <hip/hip_runtime.h>
#include <math.h>

#define N_NODES 50000
#define N_EDGES 800000
#define IN_DIM  128
#define OUT_DIM 64
#define LEAKY   0.01f

#define PROJ_ROWS 64
#define PROJ_NB   ((N_NODES + PROJ_ROWS - 1) / PROJ_ROWS)   // 782

#define SCAN_B   1024
#define SCAN_NB  ((N_NODES + SCAN_B - 1) / SCAN_B)          // 49

// ---------------------------------------------------------------------------
// z = feat @ W, az epilogue. 256 threads, 64 rows/block, feat tile in LDS.
// Wave w computes rows [w*16, w*16+16), lane = output col. Inner loop:
// per 4-k chunk: 16 uniform ds_read_b128 (broadcast, conflict-free) +
// 4 L1-hot W loads + 64 FMAs.
__global__ __launch_bounds__(256) void proj_kernel(
        const float* __restrict__ feat, const float* __restrict__ W,
        const float* __restrict__ a,
        float* __restrict__ z, float* __restrict__ az_src, float* __restrict__ az_dst) {
    __shared__ float fs[PROJ_ROWS * IN_DIM];                // 32 KB
    int tid  = threadIdx.x;
    int row0 = blockIdx.x * PROJ_ROWS;
    int nrows = N_NODES - row0; if (nrows > PROJ_ROWS) nrows = PROJ_ROWS;

    // stage feat tile: 2048 float4, 8 per thread, coalesced
    const float4* gsrc = (const float4*)(feat + (size_t)row0 * IN_DIM);
    if (nrows == PROJ_ROWS) {
#pragma unroll
        for (int i = 0; i < 8; ++i) {
            int idx = tid + i * 256;
            ((float4*)fs)[idx] = gsrc[idx];
        }
    } else {
        int lim = nrows * (IN_DIM / 4);
#pragma unroll
        for (int i = 0; i < 8; ++i) {
            int idx = tid + i * 256;
            if (idx < lim) ((float4*)fs)[idx] = gsrc[idx];
        }
    }
    __syncthreads();

    int lane  = tid & 63;
    int rbase = (tid >> 6) * 16;

    float acc[16];
#pragma unroll
    for (int r = 0; r < 16; ++r) acc[r] = 0.f;

    for (int kk = 0; kk < IN_DIM / 4; ++kk) {
        float w0 = W[(kk * 4 + 0) * OUT_DIM + lane];
        float w1 = W[(kk * 4 + 1) * OUT_DIM + lane];
        float w2 = W[(kk * 4 + 2) * OUT_DIM + lane];
        float w3 = W[(kk * 4 + 3) * OUT_DIM + lane];
#pragma unroll
        for (int r = 0; r < 16; ++r) {
            float4 f = *(const float4*)&fs[(rbase + r) * IN_DIM + kk * 4];
            acc[r] = fmaf(f.x, w0, acc[r]);
            acc[r] = fmaf(f.y, w1, acc[r]);
            acc[r] = fmaf(f.z, w2, acc[r]);
            acc[r] = fmaf(f.w, w3, acc[r]);
        }
    }

    float a1 = a[lane], a2 = a[OUT_DIM + lane];
#pragma unroll
    for (int r = 0; r < 16; ++r) {
        int row = row0 + rbase + r;
        if (row < N_NODES) {
            z[(size_t)row * OUT_DIM + lane] = acc[r];
            float s1 = acc[r] * a1;
            float s2 = acc[r] * a2;
#pragma unroll
            for (int off = 32; off > 0; off >>= 1) {
                s1 += __shfl_xor(s1, off, 64);
                s2 += __shfl_xor(s2, off, 64);
            }
            if (lane == r) { az_src[row] = s1; az_dst[row] = s2; }
        }
    }
}

// ---------------------------------------------------------------------------
// degree histogram
__global__ __launch_bounds__(256) void hist_kernel(
        const int* __restrict__ dst, int* __restrict__ counts) {
    int i = blockIdx.x * 256 + threadIdx.x;
    if (i < N_EDGES) atomicAdd(&counts[dst[i]], 1);
}

// ---------------------------------------------------------------------------
// scan step 1: per-block exclusive scan, block totals out
__global__ __launch_bounds__(SCAN_B) void scan1_kernel(
        const int* __restrict__ counts, int* __restrict__ offsets,
        int* __restrict__ blocksums) {
    __shared__ int s[SCAN_B];
    int i = blockIdx.x * SCAN_B + threadIdx.x;
    int v = (i < N_NODES) ? counts[i] : 0;
    s[threadIdx.x] = v;
    __syncthreads();
    for (int off = 1; off < SCAN_B; off <<= 1) {
        int t = (threadIdx.x >= off) ? s[threadIdx.x - off] : 0;
        __syncthreads();
        s[threadIdx.x] += t;
        __syncthreads();
    }
    if (i < N_NODES) offsets[i] = s[threadIdx.x] - v;
    if (threadIdx.x == SCAN_B - 1) blocksums[blockIdx.x] = s[SCAN_B - 1];
}

// scan step 2+3 fused: every block wave-scans the 49 block sums itself,
// then adds its block offset; init cursor; seal offsets[N]
__global__ __launch_bounds__(SCAN_B) void scan3_kernel(
        int* __restrict__ offsets, int* __restrict__ cursor,
        const int* __restrict__ blocksums) {
    __shared__ int bs[64];
    if (threadIdx.x < 64) {
        int lane = threadIdx.x;                       // wave 0 lanes
        int v = (lane < SCAN_NB) ? blocksums[lane] : 0;
        int inc = v;
#pragma unroll
        for (int off = 1; off < 64; off <<= 1) {
            int t = __shfl_up(inc, off, 64);
            if (lane >= off) inc += t;
        }
        bs[lane] = inc - v;                           // exclusive
    }
    __syncthreads();
    int i = blockIdx.x * SCAN_B + threadIdx.x;
    if (i < N_NODES) {
        int o = offsets[i] + bs[blockIdx.x];
        offsets[i] = o;
        cursor[i]  = o;
    }
    if (i == 0) offsets[N_NODES] = N_EDGES;
}

// ---------------------------------------------------------------------------
// CSR build: compute exp(score) once (no max subtraction -- scores are O(5),
// exp is safe in fp32 and the max cancels in alpha), scatter ONE 8B record
// (src, exp_e), and accumulate e_sum[t] here so the node kernel is one pass.
__global__ __launch_bounds__(256) void build_csr_kernel(
        const int* __restrict__ src, const int* __restrict__ dst,
        const float* __restrict__ az_src, const float* __restrict__ az_dst,
        int* __restrict__ cursor, float2* __restrict__ edge_rec,
        float* __restrict__ e_sum) {
    int i = blockIdx.x * 256 + threadIdx.x;
    if (i >= N_EDGES) return;
    int s = src[i], t = dst[i];
    float v = az_src[s] + az_dst[t];
    float e = v > 0.f ? v : LEAKY * v;
    float ex = __expf(e);
    int pos = atomicAdd(&cursor[t], 1);
    float2 rec;
    rec.x = __int_as_float(s);
    rec.y = ex;
    edge_rec[pos] = rec;
    atomicAdd(&e_sum[t], ex);
}

// ---------------------------------------------------------------------------
// single-pass weighted aggregation. One wave per node, lane = dim.
// 4 independent accumulators -> 4 outstanding 256B row gathers.
__global__ __launch_bounds__(256) void node_fused_kernel(
        const int* __restrict__ offsets, const float2* __restrict__ edge_rec,
        const float* __restrict__ e_sum,
        const float* __restrict__ z, float* __restrict__ h) {
    int lane = threadIdx.x & 63;
    int w    = threadIdx.x >> 6;
    int t    = blockIdx.x * 4 + w;
    if (t >= N_NODES) return;
    int beg = offsets[t];
    int end = offsets[t + 1];

    float acc0 = 0.f, acc1 = 0.f, acc2 = 0.f, acc3 = 0.f;
    int i = beg;
    for (; i + 4 <= end; i += 4) {
        float2 r0 = edge_rec[i];
        float2 r1 = edge_rec[i + 1];
        float2 r2 = edge_rec[i + 2];
        float2 r3 = edge_rec[i + 3];
        const float* z0 = z + (size_t)__float_as_int(r0.x) * OUT_DIM;
        const float* z1 = z + (size_t)__float_as_int(r1.x) * OUT_DIM;
        const float* z2 = z + (size_t)__float_as_int(r2.x) * OUT_DIM;
        const float* z3 = z + (size_t)__float_as_int(r3.x) * OUT_DIM;
        acc0 = fmaf(r0.y, z0[lane], acc0);
        acc1 = fmaf(r1.y, z1[lane], acc1);
        acc2 = fmaf(r2.y, z2[lane], acc2);
        acc3 = fmaf(r3.y, z3[lane], acc3);
    }
    for (; i < end; ++i) {
        float2 rr = edge_rec[i];
        acc0 = fmaf(rr.y, z[(size_t)__float_as_int(rr.x) * OUT_DIM + lane], acc0);
    }
    float inv = (end > beg) ? 1.f / e_sum[t] : 0.f;
    h[(size_t)t * OUT_DIM + lane] = ((acc0 + acc1) + (acc2 + acc3)) * inv;
}

// ---------------------------------------------------------------------------
extern "C" void kernel_launch(void* const* d_in, const int* in_sizes, int n_in,
                              void* d_out, int out_size, void* d_ws, size_t ws_size,
                              hipStream_t stream) {
    const float* feat = (const float*)d_in[0];
    const int*   src  = (const int*)  d_in[1];
    const int*   dst  = (const int*)  d_in[2];
    const float* W    = (const float*)d_in[3];
    const float* a    = (const float*)d_in[4];
    float* h = (float*)d_out;

    // workspace layout (edge_rec first for 8B alignment; counts+e_sum adjacent
    // so one memset clears both)
    float2* edge_rec  = (float2*)d_ws;                       // E float2
    float*  z         = (float*)(edge_rec + N_EDGES);        // N*64
    float*  az_src    = z + (size_t)N_NODES * OUT_DIM;
    float*  az_dst    = az_src + N_NODES;
    int*    counts    = (int*)(az_dst + N_NODES);            // N  \ one memset
    float*  e_sum     = (float*)(counts + N_NODES);          // N  /
    int*    offsets   = (int*)(e_sum + N_NODES);             // N+1
    int*    cursor    = offsets + N_NODES + 1;               // N
    int*    blocksums = cursor + N_NODES;                    // 64

    hipMemsetAsync(counts, 0, sizeof(int) * 2 * N_NODES, stream);

    int eblocks = (N_EDGES + 255) / 256;
    hist_kernel<<<eblocks, 256, 0, stream>>>(dst, counts);
    scan1_kernel<<<SCAN_NB, SCAN_B, 0, stream>>>(counts, offsets, blocksums);
    scan3_kernel<<<SCAN_NB, SCAN_B, 0, stream>>>(offsets, cursor, blocksums);

    proj_kernel<<<PROJ_NB, 256, 0, stream>>>(feat, W, a, z, az_src, az_dst);

    build_csr_kernel<<<eblocks, 256, 0, stream>>>(src, dst, az_src, az_dst,
                                                  cursor, edge_rec, e_sum);

    node_fused_kernel<<<(N_NODES + 3) / 4, 256, 0, stream>>>(
        offsets, edge_rec, e_sum, z, h);
}

// Round 5
// 202.067 us; speedup vs baseline: 1.5068x; 1.3274x over previous
//
#include <hip/hip_runtime.h>
#include <hip/hip_bf16.h>
#include <math.h>

#define N_NODES 50000
#define N_EDGES 800000
#define IN_DIM  128
#define OUT_DIM 64
#define LEAKY   0.01f

#define PROJ_ROWS 64
#define PROJ_NB   ((N_NODES + PROJ_ROWS - 1) / PROJ_ROWS)   // 782

#define SCAN_B   1024
#define SCAN_NB  ((N_NODES + SCAN_B - 1) / SCAN_B)          // 49

// ---------------------------------------------------------------------------
// z = feat @ W (stored bf16), az epilogue. 256 threads, 64 rows/block,
// feat tile in LDS. Wave w computes rows [w*16, w*16+16), lane = output col.
__global__ __launch_bounds__(256) void proj_kernel(
        const float* __restrict__ feat, const float* __restrict__ W,
        const float* __restrict__ a,
        __hip_bfloat16* __restrict__ zb,
        float* __restrict__ az_src, float* __restrict__ az_dst) {
    __shared__ float fs[PROJ_ROWS * IN_DIM];                // 32 KB
    int tid  = threadIdx.x;
    int row0 = blockIdx.x * PROJ_ROWS;
    int nrows = N_NODES - row0; if (nrows > PROJ_ROWS) nrows = PROJ_ROWS;

    const float4* gsrc = (const float4*)(feat + (size_t)row0 * IN_DIM);
    if (nrows == PROJ_ROWS) {
#pragma unroll
        for (int i = 0; i < 8; ++i) {
            int idx = tid + i * 256;
            ((float4*)fs)[idx] = gsrc[idx];
        }
    } else {
        int lim = nrows * (IN_DIM / 4);
#pragma unroll
        for (int i = 0; i < 8; ++i) {
            int idx = tid + i * 256;
            if (idx < lim) ((float4*)fs)[idx] = gsrc[idx];
        }
    }
    __syncthreads();

    int lane  = tid & 63;
    int rbase = (tid >> 6) * 16;

    float acc[16];
#pragma unroll
    for (int r = 0; r < 16; ++r) acc[r] = 0.f;

    for (int kk = 0; kk < IN_DIM / 4; ++kk) {
        float w0 = W[(kk * 4 + 0) * OUT_DIM + lane];
        float w1 = W[(kk * 4 + 1) * OUT_DIM + lane];
        float w2 = W[(kk * 4 + 2) * OUT_DIM + lane];
        float w3 = W[(kk * 4 + 3) * OUT_DIM + lane];
#pragma unroll
        for (int r = 0; r < 16; ++r) {
            float4 f = *(const float4*)&fs[(rbase + r) * IN_DIM + kk * 4];
            acc[r] = fmaf(f.x, w0, acc[r]);
            acc[r] = fmaf(f.y, w1, acc[r]);
            acc[r] = fmaf(f.z, w2, acc[r]);
            acc[r] = fmaf(f.w, w3, acc[r]);
        }
    }

    float a1 = a[lane], a2 = a[OUT_DIM + lane];
#pragma unroll
    for (int r = 0; r < 16; ++r) {
        int row = row0 + rbase + r;
        if (row < N_NODES) {
            zb[(size_t)row * OUT_DIM + lane] = __float2bfloat16(acc[r]);
            float s1 = acc[r] * a1;
            float s2 = acc[r] * a2;
#pragma unroll
            for (int off = 32; off > 0; off >>= 1) {
                s1 += __shfl_xor(s1, off, 64);
                s2 += __shfl_xor(s2, off, 64);
            }
            if (lane == r) { az_src[row] = s1; az_dst[row] = s2; }
        }
    }
}

// ---------------------------------------------------------------------------
// degree histogram + per-edge rank within its dst bucket (coalesced write)
__global__ __launch_bounds__(256) void hist_kernel(
        const int* __restrict__ dst, int* __restrict__ counts,
        int* __restrict__ rank) {
    int i = blockIdx.x * 256 + threadIdx.x;
    if (i < N_EDGES) rank[i] = atomicAdd(&counts[dst[i]], 1);
}

// ---------------------------------------------------------------------------
// scan step 1: per-block exclusive scan, block totals out
__global__ __launch_bounds__(SCAN_B) void scan1_kernel(
        const int* __restrict__ counts, int* __restrict__ offsets,
        int* __restrict__ blocksums) {
    __shared__ int s[SCAN_B];
    int i = blockIdx.x * SCAN_B + threadIdx.x;
    int v = (i < N_NODES) ? counts[i] : 0;
    s[threadIdx.x] = v;
    __syncthreads();
    for (int off = 1; off < SCAN_B; off <<= 1) {
        int t = (threadIdx.x >= off) ? s[threadIdx.x - off] : 0;
        __syncthreads();
        s[threadIdx.x] += t;
        __syncthreads();
    }
    if (i < N_NODES) offsets[i] = s[threadIdx.x] - v;
    if (threadIdx.x == SCAN_B - 1) blocksums[blockIdx.x] = s[SCAN_B - 1];
}

// scan step 2+3 fused: every block wave-scans the 49 block sums itself,
// then adds its block offset; seal offsets[N]
__global__ __launch_bounds__(SCAN_B) void scan3_kernel(
        int* __restrict__ offsets, const int* __restrict__ blocksums) {
    __shared__ int bs[64];
    if (threadIdx.x < 64) {
        int lane = threadIdx.x;
        int v = (lane < SCAN_NB) ? blocksums[lane] : 0;
        int inc = v;
#pragma unroll
        for (int off = 1; off < 64; off <<= 1) {
            int t = __shfl_up(inc, off, 64);
            if (lane >= off) inc += t;
        }
        bs[lane] = inc - v;
    }
    __syncthreads();
    int i = blockIdx.x * SCAN_B + threadIdx.x;
    if (i < N_NODES) offsets[i] += bs[blockIdx.x];
    if (i == 0) offsets[N_NODES] = N_EDGES;
}

// ---------------------------------------------------------------------------
// CSR build, atomic-free: pos = offsets[dst] + rank. ONE 4B scatter per edge
// into a 3.2MB buffer (fits per-XCD L2 -> minimal write amplification).
__global__ __launch_bounds__(256) void build_csr_kernel(
        const int* __restrict__ src, const int* __restrict__ dst,
        const int* __restrict__ rank, const int* __restrict__ offsets,
        int* __restrict__ src_sorted) {
    int i = blockIdx.x * 256 + threadIdx.x;
    if (i >= N_EDGES) return;
    int t = dst[i];
    int pos = offsets[t] + rank[i];    // offsets L2-hot (200KB)
    src_sorted[pos] = src[i];
}

// ---------------------------------------------------------------------------
// single-pass softmax-aggregation. One wave per node, lane = dim.
// e recomputed from az (L2-hot); ssum lane-redundant (no reduction needed).
__global__ __launch_bounds__(256) void node_fused_kernel(
        const int* __restrict__ offsets, const int* __restrict__ src_sorted,
        const float* __restrict__ az_src, const float* __restrict__ az_dst,
        const __hip_bfloat16* __restrict__ zb, float* __restrict__ h) {
    int lane = threadIdx.x & 63;
    int w    = threadIdx.x >> 6;
    int t    = blockIdx.x * 4 + w;
    if (t >= N_NODES) return;
    int beg = offsets[t];
    int end = offsets[t + 1];
    float az_d = az_dst[t];

    float acc0 = 0.f, acc1 = 0.f, acc2 = 0.f, acc3 = 0.f;
    float ss0 = 0.f, ss1 = 0.f, ss2 = 0.f, ss3 = 0.f;
    int i = beg;
    for (; i + 4 <= end; i += 4) {
        int s0 = src_sorted[i];
        int s1 = src_sorted[i + 1];
        int s2 = src_sorted[i + 2];
        int s3 = src_sorted[i + 3];
        float v0 = az_src[s0] + az_d;
        float v1 = az_src[s1] + az_d;
        float v2 = az_src[s2] + az_d;
        float v3 = az_src[s3] + az_d;
        v0 = v0 > 0.f ? v0 : LEAKY * v0;
        v1 = v1 > 0.f ? v1 : LEAKY * v1;
        v2 = v2 > 0.f ? v2 : LEAKY * v2;
        v3 = v3 > 0.f ? v3 : LEAKY * v3;
        float x0 = __expf(v0), x1 = __expf(v1);
        float x2 = __expf(v2), x3 = __expf(v3);
        ss0 += x0; ss1 += x1; ss2 += x2; ss3 += x3;
        acc0 = fmaf(x0, __bfloat162float(zb[(size_t)s0 * OUT_DIM + lane]), acc0);
        acc1 = fmaf(x1, __bfloat162float(zb[(size_t)s1 * OUT_DIM + lane]), acc1);
        acc2 = fmaf(x2, __bfloat162float(zb[(size_t)s2 * OUT_DIM + lane]), acc2);
        acc3 = fmaf(x3, __bfloat162float(zb[(size_t)s3 * OUT_DIM + lane]), acc3);
    }
    for (; i < end; ++i) {
        int s0 = src_sorted[i];
        float v0 = az_src[s0] + az_d;
        v0 = v0 > 0.f ? v0 : LEAKY * v0;
        float x0 = __expf(v0);
        ss0 += x0;
        acc0 = fmaf(x0, __bfloat162float(zb[(size_t)s0 * OUT_DIM + lane]), acc0);
    }
    float ssum = (ss0 + ss1) + (ss2 + ss3);
    float inv  = (end > beg) ? 1.f / ssum : 0.f;
    h[(size_t)t * OUT_DIM + lane] = ((acc0 + acc1) + (acc2 + acc3)) * inv;
}

// ---------------------------------------------------------------------------
extern "C" void kernel_launch(void* const* d_in, const int* in_sizes, int n_in,
                              void* d_out, int out_size, void* d_ws, size_t ws_size,
                              hipStream_t stream) {
    const float* feat = (const float*)d_in[0];
    const int*   src  = (const int*)  d_in[1];
    const int*   dst  = (const int*)  d_in[2];
    const float* W    = (const float*)d_in[3];
    const float* a    = (const float*)d_in[4];
    float* h = (float*)d_out;

    // workspace layout (4B-aligned arrays first, bf16 z last)
    float* az_src     = (float*)d_ws;                        // N
    float* az_dst     = az_src + N_NODES;                    // N
    int*   counts     = (int*)(az_dst + N_NODES);            // N
    int*   offsets    = counts + N_NODES;                    // N+1
    int*   blocksums  = offsets + N_NODES + 1;               // 64
    int*   rank       = blocksums + 64;                      // E
    int*   src_sorted = rank + N_EDGES;                      // E
    __hip_bfloat16* zb = (__hip_bfloat16*)(src_sorted + N_EDGES); // N*64

    hipMemsetAsync(counts, 0, sizeof(int) * N_NODES, stream);

    int eblocks = (N_EDGES + 255) / 256;
    hist_kernel<<<eblocks, 256, 0, stream>>>(dst, counts, rank);
    scan1_kernel<<<SCAN_NB, SCAN_B, 0, stream>>>(counts, offsets, blocksums);
    scan3_kernel<<<SCAN_NB, SCAN_B, 0, stream>>>(offsets, blocksums);

    proj_kernel<<<PROJ_NB, 256, 0, stream>>>(feat, W, a, zb, az_src, az_dst);

    build_csr_kernel<<<eblocks, 256, 0, stream>>>(src, dst, rank, offsets,
                                                  src_sorted);

    node_fused_kernel<<<(N_NODES + 3) / 4, 256, 0, stream>>>(
        offsets, src_sorted, az_src, az_dst, zb, h);
}